// Round 2
// baseline (3738.041 us; speedup 1.0000x reference)
//
#include <hip/hip_runtime.h>
#include <hip/hip_bf16.h>

#define B_   256
#define P_   100
#define H_   512
#define NH_  16
#define HD_  32
#define VN_  221
#define KNODE 201
#define KVEH  21
#define KVND  20
#define KTOT 463
#define CSD_ 16
#define MASKN (B_ * P_ * VN_)   // 5,657,600 mask elements

// ---- LDS layout for attention kernel (f32 units) ----
constexpr int KS_F = KTOT * 32;      // 14816  swizzled row-major K concat
constexpr int VT_STRIDE = 476;       // transposed V row length (pad)
constexpr int VT_F = 32 * VT_STRIDE; // 15232
constexpr int QS_F = P_ * 32;        // 3200
constexpr int WB_F = 4 * 512;        // 2048 per-wave weight buffers
constexpr int ATTN_LDS_F = KS_F + VT_F + QS_F + WB_F;   // 35296 f32 = 141184 B

// ------------------------------------------------------------------
// mask dtype probe: if any of the first 4096 words is not 0/1, the
// buffer is packed uint8 bools; else it is int32 bools.
// (bernoulli p=0.3 -> P[all 4096 uint8-words ambiguous] = 0.343^4096 ~ 0)
// ------------------------------------------------------------------
__global__ void mask_detect_kernel(const unsigned int* __restrict__ w,
                                   int nwords, int* __restrict__ flag) {
    int i = blockIdx.x * 256 + threadIdx.x;
    if (i < nwords && (w[i] & ~1u)) atomicOr(flag, 1);
}

__global__ void mask_repack_kernel(const unsigned char* __restrict__ mb,
                                   const int* __restrict__ mw,
                                   const int* __restrict__ flag,
                                   unsigned char* __restrict__ out, int n) {
    int i = blockIdx.x * blockDim.x + threadIdx.x;
    if (i < n) out[i] = (*flag) ? (unsigned char)(mb[i] != 0)
                                : (unsigned char)(mw[i] != 0);
}

// ------------------------------------------------------------------
// per-source attention: QK^T key-parallel, softmax, PV dim-parallel
// ------------------------------------------------------------------
template<int LEN, bool MASKED>
__device__ __forceinline__ void attend_src(
    const float* __restrict__ Ks, const float* __restrict__ Vt,
    float* __restrict__ wb, const float (&qv)[32],
    const unsigned char* __restrict__ mrow,
    int lane, int roff, int voff, float& acc)
{
    constexpr int NK = (LEN + 63) / 64;
    float s[NK];
    float m = -1e30f;
    #pragma unroll
    for (int i = 0; i < NK; i++) {
        int kl = lane + i * 64;
        float sc = -1e30f;
        if (kl < LEN) {
            int rr = roff + kl;
            const float* kr = Ks + rr * 32;
            int sw = (rr & 7) << 2;
            float dot = 0.f;
            #pragma unroll
            for (int j = 0; j < 8; j++) {
                const float4 k4 = *(const float4*)(kr + ((j * 4) ^ sw));
                dot += qv[4*j+0]*k4.x + qv[4*j+1]*k4.y + qv[4*j+2]*k4.z + qv[4*j+3]*k4.w;
            }
            sc = dot * 0.17677669529663687f;   // 32^-0.5
            if (MASKED) { if (mrow[kl]) sc = -1e30f; }
        }
        s[i] = sc;
        m = fmaxf(m, sc);
    }
    #pragma unroll
    for (int off = 32; off > 0; off >>= 1) m = fmaxf(m, __shfl_xor(m, off));
    float sum = 0.f;
    #pragma unroll
    for (int i = 0; i < NK; i++) {
        float e = (s[i] > -1e29f) ? __expf(s[i] - m) : 0.f;
        s[i] = e;
        sum += e;
    }
    #pragma unroll
    for (int off = 32; off > 0; off >>= 1) sum += __shfl_xor(sum, off);
    const float inv = 1.f / sum;   // >=1 valid key per source guaranteed
    #pragma unroll
    for (int i = 0; i < NK; i++) {
        int kl = lane + i * 64;
        if (kl < LEN) wb[kl] = s[i] * inv;
    }
    // my wave's ds_writes must land before my dim-parallel reads
    asm volatile("s_waitcnt lgkmcnt(0)" ::: "memory");

    const int d = lane & 31, half = lane >> 5;
    const float* vrow = Vt + d * VT_STRIDE + voff;
    float pacc = 0.f;
    constexpr int NCH = LEN / 8;           // chunks of 8 keys (4 per half)
    #pragma unroll 4
    for (int c = 0; c < NCH; c++) {
        int k0 = c * 8 + half * 4;
        float4 w4 = *(const float4*)(wb + k0);
        float4 v4 = *(const float4*)(vrow + k0);
        pacc += w4.x*v4.x + w4.y*v4.y + w4.z*v4.z + w4.w*v4.w;
    }
    #pragma unroll
    for (int k = NCH * 8 + half; k < LEN; k += 2)
        pacc += wb[k] * vrow[k];
    acc += pacc;
}

// ------------------------------------------------------------------
// attention: one block per (b, nh); K/V/Q staged in LDS
// ------------------------------------------------------------------
__global__ __launch_bounds__(256) void attn_kernel(
    const float* __restrict__ q4,                       // [B,NH,P,HD]
    const float* __restrict__ kg,  const float* __restrict__ vg,
    const float* __restrict__ kn,  const float* __restrict__ vnd,
    const float* __restrict__ kv,  const float* __restrict__ vv,
    const float* __restrict__ kvn, const float* __restrict__ vvn,
    const unsigned char* __restrict__ mask,             // canonical [B*P, VN] u8
    float* __restrict__ ctx_out)                        // [B*P, H]
{
    extern __shared__ float lds[];
    float* Ks   = lds;
    float* Vt   = lds + KS_F;
    float* qs   = Vt + VT_F;
    float* wbuf = qs + QS_F;

    const int tid = threadIdx.x;
    const int bh  = blockIdx.x;          // b*16 + nh
    const int b   = bh >> 4;

    // stage K (swizzled row-major, concatenated sources)
    {
        const float* srcs[4] = { kg, kn, kv, kvn };
        const int rows[4]    = { VN_, KNODE, KVEH, KVND };
        const int roffs[4]   = { 0, 221, 422, 443 };
        for (int sI = 0; sI < 4; sI++) {
            const float4* s4 = (const float4*)(srcs[sI] + (size_t)bh * rows[sI] * 32);
            int n4 = rows[sI] * 8;
            for (int i = tid; i < n4; i += 256) {
                int r = i >> 3, jj = i & 7;
                int rr = roffs[sI] + r;
                float4 v = s4[i];
                *(float4*)(Ks + rr * 32 + ((jj * 4) ^ ((rr & 7) << 2))) = v;
            }
        }
    }
    // stage V transposed [32][476]
    {
        const float* srcs[4] = { vg, vnd, vv, vvn };
        const int rows[4]    = { VN_, KNODE, KVEH, KVND };
        const int voffs[4]   = { 0, 224, 428, 452 };     // 4-aligned column starts
        for (int sI = 0; sI < 4; sI++) {
            const float* s = srcs[sI] + (size_t)bh * rows[sI] * 32;
            int n = rows[sI] * 32;
            for (int i = tid; i < n; i += 256) {
                int r = i >> 5, d = i & 31;
                Vt[d * VT_STRIDE + voffs[sI] + r] = s[i];
            }
        }
    }
    // stage Q
    {
        const float4* qsrc = (const float4*)(q4 + (size_t)bh * P_ * 32);
        for (int i = tid; i < P_ * 8; i += 256) ((float4*)qs)[i] = qsrc[i];
    }
    __syncthreads();

    const int wave = tid >> 6, lane = tid & 63;
    float* wb = wbuf + wave * 512;

    for (int p = wave; p < P_; p += 4) {
        float qv[32];
        #pragma unroll
        for (int j = 0; j < 8; j++) {
            float4 t = *(const float4*)(qs + p * 32 + 4 * j);
            qv[4*j+0] = t.x; qv[4*j+1] = t.y; qv[4*j+2] = t.z; qv[4*j+3] = t.w;
        }
        const unsigned char* mrow = mask + (size_t)(b * P_ + p) * VN_;
        float acc = 0.f;
        attend_src<VN_,  true >(Ks, Vt, wb, qv, mrow, lane, 0,   0,   acc);
        attend_src<KNODE,false>(Ks, Vt, wb, qv, mrow, lane, 221, 224, acc);
        attend_src<KVEH, false>(Ks, Vt, wb, qv, mrow, lane, 422, 428, acc);
        attend_src<KVND, false>(Ks, Vt, wb, qv, mrow, lane, 443, 452, acc);
        acc += __shfl_xor(acc, 32);
        if (lane < 32) {
            int nh = bh & 15;
            ctx_out[(size_t)(b * P_ + p) * H_ + nh * 32 + lane] = acc;
        }
    }
}

// ------------------------------------------------------------------
// q-projection GEMM: [25600,528] x Wq^T -> q4 [B,NH,P,HD]
// ------------------------------------------------------------------
__global__ __launch_bounds__(256) void qproj_kernel(
    const float* __restrict__ qg, const float* __restrict__ cf,
    const float* __restrict__ Wq, float* __restrict__ q4)
{
    __shared__ float As[16][65];
    __shared__ float Bs[16][68];
    const int tid = threadIdx.x;
    const int tx = tid & 15, ty = tid >> 4;
    const int n0 = blockIdx.x * 64;
    const int m0 = blockIdx.y * 64;
    float acc[4][4] = {};
    for (int kc = 0; kc < 528; kc += 16) {
        #pragma unroll
        for (int i = 0; i < 4; i++) {
            int lin = tid + i * 256;
            int k = lin & 15, m = lin >> 4;
            int gk = kc + k;
            int row = m0 + m;
            As[k][m] = (gk < 512) ? qg[(size_t)row * 512 + gk]
                                  : cf[(size_t)row * 16 + (gk - 512)];
            Bs[k][m] = Wq[(size_t)(n0 + m) * 528 + gk];
        }
        __syncthreads();
        #pragma unroll
        for (int kk = 0; kk < 16; kk++) {
            float a[4];
            #pragma unroll
            for (int i = 0; i < 4; i++) a[i] = As[kk][ty * 4 + i];
            float4 b4 = *(const float4*)(&Bs[kk][tx * 4]);
            float bv[4] = { b4.x, b4.y, b4.z, b4.w };
            #pragma unroll
            for (int i = 0; i < 4; i++)
                #pragma unroll
                for (int j = 0; j < 4; j++)
                    acc[i][j] += a[i] * bv[j];
        }
        __syncthreads();
    }
    #pragma unroll
    for (int i = 0; i < 4; i++) {
        int row = m0 + ty * 4 + i;
        int bb = row / 100, p = row % 100;
        #pragma unroll
        for (int j = 0; j < 4; j++) {
            int col = n0 + tx * 4 + j;
            int nh = col >> 5, d = col & 31;
            q4[(((size_t)bb * NH_ + nh) * P_ + p) * HD_ + d] = acc[i][j];
        }
    }
}

// ------------------------------------------------------------------
// combine GEMM: [25600,512] x Wc^T + bias -> mha [25600,512]
// ------------------------------------------------------------------
__global__ __launch_bounds__(256) void combine_kernel(
    const float* __restrict__ ctx, const float* __restrict__ Wc,
    const float* __restrict__ bias, float* __restrict__ mha)
{
    __shared__ float As[16][65];
    __shared__ float Bs[16][68];
    const int tid = threadIdx.x;
    const int tx = tid & 15, ty = tid >> 4;
    const int n0 = blockIdx.x * 64;
    const int m0 = blockIdx.y * 64;
    float acc[4][4] = {};
    for (int kc = 0; kc < 512; kc += 16) {
        #pragma unroll
        for (int i = 0; i < 4; i++) {
            int lin = tid + i * 256;
            int k = lin & 15, m = lin >> 4;
            int gk = kc + k;
            As[k][m] = ctx[(size_t)(m0 + m) * 512 + gk];
            Bs[k][m] = Wc[(size_t)(n0 + m) * 512 + gk];
        }
        __syncthreads();
        #pragma unroll
        for (int kk = 0; kk < 16; kk++) {
            float a[4];
            #pragma unroll
            for (int i = 0; i < 4; i++) a[i] = As[kk][ty * 4 + i];
            float4 b4 = *(const float4*)(&Bs[kk][tx * 4]);
            float bv[4] = { b4.x, b4.y, b4.z, b4.w };
            #pragma unroll
            for (int i = 0; i < 4; i++)
                #pragma unroll
                for (int j = 0; j < 4; j++)
                    acc[i][j] += a[i] * bv[j];
        }
        __syncthreads();
    }
    #pragma unroll
    for (int i = 0; i < 4; i++) {
        int row = m0 + ty * 4 + i;
        #pragma unroll
        for (int j = 0; j < 4; j++) {
            int col = n0 + tx * 4 + j;
            mha[(size_t)row * 512 + col] = acc[i][j] + bias[col];
        }
    }
}

// ------------------------------------------------------------------
// logits: out[b,p,k] = sum_h mha[b,p,h] * cp[b,h,k]
// block = (b, 25-row chunk); thread = k
// ------------------------------------------------------------------
__global__ __launch_bounds__(256) void logits_kernel(
    const float* __restrict__ mha,   // [B*P, 512]
    const float* __restrict__ cp,    // [B, 512, VN]
    float* __restrict__ out)         // [B*P, VN]
{
    __shared__ float sm[25 * 512];
    const int tid = threadIdx.x;
    const int b  = blockIdx.x >> 2;
    const int p0 = (blockIdx.x & 3) * 25;

    const float4* msrc = (const float4*)(mha + ((size_t)b * P_ + p0) * 512);
    for (int i = tid; i < 25 * 128; i += 256) ((float4*)sm)[i] = msrc[i];
    __syncthreads();

    const int k = tid;
    if (k < VN_) {
        const float* cpb = cp + (size_t)b * 512 * VN_;
        float acc[25] = {};
        for (int h = 0; h < 512; h += 4) {
            float c0 = cpb[(size_t)(h + 0) * VN_ + k];
            float c1 = cpb[(size_t)(h + 1) * VN_ + k];
            float c2 = cpb[(size_t)(h + 2) * VN_ + k];
            float c3 = cpb[(size_t)(h + 3) * VN_ + k];
            #pragma unroll
            for (int p = 0; p < 25; p++) {
                float4 m4 = *(const float4*)(sm + p * 512 + h);
                acc[p] += m4.x * c0 + m4.y * c1 + m4.z * c2 + m4.w * c3;
            }
        }
        #pragma unroll
        for (int p = 0; p < 25; p++)
            out[((size_t)b * P_ + p0 + p) * VN_ + k] = acc[p];
    }
}

// ------------------------------------------------------------------
extern "C" void kernel_launch(void* const* d_in, const int* in_sizes, int n_in,
                              void* d_out, int out_size, void* d_ws, size_t ws_size,
                              hipStream_t stream) {
    const float* qg   = (const float*)d_in[0];
    const float* kgl  = (const float*)d_in[1];
    const float* vgl  = (const float*)d_in[2];
    const float* knd  = (const float*)d_in[3];
    const float* vnd  = (const float*)d_in[4];
    const float* kvh  = (const float*)d_in[5];
    const float* vvh  = (const float*)d_in[6];
    const float* kvnd = (const float*)d_in[7];
    const float* vvnd = (const float*)d_in[8];
    const float* cf   = (const float*)d_in[9];
    const float* cp   = (const float*)d_in[10];
    const void*  mask_raw = d_in[11];
    const float* Wq   = (const float*)d_in[12];
    const float* Wc   = (const float*)d_in[13];
    const float* bias = (const float*)d_in[14];
    float* out = (float*)d_out;

    const size_t NQ = (size_t)B_ * NH_ * P_ * HD_;   // 13,107,200 f32
    float* q4buf  = (float*)d_ws;
    float* ctxbuf = q4buf + NQ;
    float* mhabuf = q4buf;                            // reuse: q dead after attn
    unsigned char* mask8 = (unsigned char*)(ctxbuf + NQ);
    int* flag = (int*)(mask8 + ((MASKN + 15) & ~15));

    hipFuncSetAttribute(reinterpret_cast<const void*>(attn_kernel),
                        hipFuncAttributeMaxDynamicSharedMemorySize,
                        ATTN_LDS_F * 4);

    // ---- canonicalize mask (handles int32 or uint8 device layout) ----
    hipMemsetAsync(flag, 0, sizeof(int), stream);
    mask_detect_kernel<<<16, 256, 0, stream>>>(
        (const unsigned int*)mask_raw, 4096, flag);
    mask_repack_kernel<<<(MASKN + 255) / 256, 256, 0, stream>>>(
        (const unsigned char*)mask_raw, (const int*)mask_raw, flag, mask8, MASKN);

    qproj_kernel<<<dim3(8, 400), 256, 0, stream>>>(qg, cf, Wq, q4buf);
    attn_kernel<<<B_ * NH_, 256, ATTN_LDS_F * 4, stream>>>(
        q4buf, kgl, vgl, knd, vnd, kvh, vvh, kvnd, vvnd, mask8, ctxbuf);
    combine_kernel<<<dim3(8, 400), 256, 0, stream>>>(ctxbuf, Wc, bias, mhabuf);
    logits_kernel<<<B_ * 4, 256, 0, stream>>>(mhabuf, cp, out);
}

// Round 3
// 973.261 us; speedup vs baseline: 3.8407x; 3.8407x over previous
//
#include <hip/hip_runtime.h>
#include <hip/hip_bf16.h>

#define B_   256
#define P_   100
#define H_   512
#define NH_  16
#define HD_  32
#define VN_  221
#define KNODE 201
#define KVEH  21
#define KVND  20
#define CSD_ 16
#define MASKP 224                       // padded mask row stride (aligned dwords)

typedef __attribute__((ext_vector_type(8))) short short8;
typedef __attribute__((ext_vector_type(4))) float f32x4;

// ---- attention LDS layout (bytes) ----
// K   : 480 rows x 80B  (32 bf16 + 16B pad; stride16=5 odd -> 2-way max)  [0, 38400)
// V^T : 32 rows  x 976B (480 keys bf16 + pad; stride16=61 odd)            [38400, 69632)
// P   : 8 waves  x 16 rows x 80B (32 keys bf16 per chunk)                 [69632, 79872)
#define K_OFF   0
#define V_OFF   38400
#define P_OFF   69632
#define ATTN_LDS_B 79872

__device__ __forceinline__ unsigned f2bf(float f) {
    union { float f; unsigned u; } x; x.f = f;
    return (x.u + 0x7FFFu + ((x.u >> 16) & 1u)) >> 16;   // RNE bf16 bits
}

// ------------------------------------------------------------------
// mask dtype probe + repack to padded [B*P][224] u8 (pad = 1 = illegal)
// ------------------------------------------------------------------
__global__ void mask_detect_kernel(const unsigned int* __restrict__ w,
                                   int nwords, int* __restrict__ flag) {
    int i = blockIdx.x * 256 + threadIdx.x;
    if (i < nwords && (w[i] & ~1u)) atomicOr(flag, 1);
}

__global__ void mask_repack_kernel(const unsigned char* __restrict__ mb,
                                   const int* __restrict__ mw,
                                   const int* __restrict__ flag,
                                   unsigned char* __restrict__ out) {
    int i = blockIdx.x * blockDim.x + threadIdx.x;
    if (i >= B_ * P_ * MASKP) return;
    int row = i / MASKP, k = i - row * MASKP;
    unsigned char v = 1;
    if (k < VN_) {
        int src = row * VN_ + k;
        v = (*flag) ? (unsigned char)(mb[src] != 0) : (unsigned char)(mw[src] != 0);
    }
    out[i] = v;
}

// ------------------------------------------------------------------
// one source's chunks: S^T = mfma(K,Q); exp; P->LDS; O^T += mfma(V^T,P)
// ------------------------------------------------------------------
template<bool MASKED>
__device__ __forceinline__ void attend_rng(
    const char* __restrict__ ldsb, char* __restrict__ Pw,
    const unsigned char* __restrict__ mrow,
    short8 qf, int g, int qr, int c0, int c1, int lo, int hi,
    f32x4& O0, f32x4& O1)
{
    f32x4 A0 = {0.f,0.f,0.f,0.f}, A1 = {0.f,0.f,0.f,0.f};
    float ssum = 0.f;
    for (int c = c0; c <= c1; ++c) {
        #pragma unroll
        for (int t = 0; t < 2; ++t) {
            const int kb = c * 32 + t * 16;
            short8 kf = *(const short8*)(ldsb + K_OFF + (size_t)(kb + qr) * 80 + g * 16);
            f32x4 s = __builtin_amdgcn_mfma_f32_16x16x32_bf16(
                          kf, qf, (f32x4){0.f,0.f,0.f,0.f}, 0, 0, 0);
            unsigned mdw = 0;
            if (MASKED) mdw = *(const unsigned*)(mrow + kb + g * 4);
            float pv[4];
            #pragma unroll
            for (int r = 0; r < 4; ++r) {
                int key = kb + g * 4 + r;
                float sv = fminf(fmaxf(s[r], -30.f), 30.f);
                float e = __expf(sv);
                bool ok = MASKED ? (((mdw >> (8 * r)) & 255u) == 0u)
                                 : (key >= lo && key < hi);
                e = ok ? e : 0.f;
                pv[r] = e;
                ssum += e;
            }
            uint2 w;
            w.x = f2bf(pv[0]) | (f2bf(pv[1]) << 16);
            w.y = f2bf(pv[2]) | (f2bf(pv[3]) << 16);
            *(uint2*)(Pw + qr * 80 + t * 32 + g * 8) = w;
        }
        // whole wave's P writes must land before cross-lane P reads
        asm volatile("s_waitcnt lgkmcnt(0)" ::: "memory");
        short8 pf = *(const short8*)(Pw + qr * 80 + g * 16);
        short8 v0 = *(const short8*)(ldsb + V_OFF + (size_t)qr        * 976 + c * 64 + g * 16);
        short8 v1 = *(const short8*)(ldsb + V_OFF + (size_t)(qr + 16) * 976 + c * 64 + g * 16);
        A0 = __builtin_amdgcn_mfma_f32_16x16x32_bf16(v0, pf, A0, 0, 0, 0);
        A1 = __builtin_amdgcn_mfma_f32_16x16x32_bf16(v1, pf, A1, 0, 0, 0);
    }
    ssum += __shfl_xor(ssum, 16);
    ssum += __shfl_xor(ssum, 32);
    const float inv = 1.f / ssum;
    O0 += A0 * inv;
    O1 += A1 * inv;
}

// ------------------------------------------------------------------
// MFMA attention: one block per (b,nh); 512 threads; K/V^T bf16 in LDS
// ------------------------------------------------------------------
__global__ __launch_bounds__(512, 4) void attn_mfma_kernel(
    const float* __restrict__ q4,                       // [B,NH,P,HD] f32
    const float* __restrict__ kg,  const float* __restrict__ vg,
    const float* __restrict__ kn,  const float* __restrict__ vn,
    const float* __restrict__ kv,  const float* __restrict__ vv,
    const float* __restrict__ kvn, const float* __restrict__ vvn,
    const unsigned char* __restrict__ maskp,            // [B*P,224] u8
    float* __restrict__ ctx_out)                        // [B*P,512]
{
    extern __shared__ char ldsb[];
    const int tid = threadIdx.x;
    const int bh = blockIdx.x, b = bh >> 4, nh = bh & 15;

    // ---- stage K as bf16 [463][80B] + zero pad rows ----
    {
        const float* srcs[4] = { kg, kn, kv, kvn };
        const int rows[4] = { VN_, KNODE, KVEH, KVND };
        const int r0s[4]  = { 0, 221, 422, 443 };
        for (int sI = 0; sI < 4; ++sI) {
            const float* sp = srcs[sI] + (size_t)bh * rows[sI] * 32;
            const int nslot = rows[sI] * 4;
            for (int lin = tid; lin < nslot; lin += 512) {
                int r = lin >> 2, s = lin & 3;
                float4 a = *(const float4*)(sp + r * 32 + s * 8);
                float4 c = *(const float4*)(sp + r * 32 + s * 8 + 4);
                uint4 w;
                w.x = f2bf(a.x) | (f2bf(a.y) << 16);
                w.y = f2bf(a.z) | (f2bf(a.w) << 16);
                w.z = f2bf(c.x) | (f2bf(c.y) << 16);
                w.w = f2bf(c.z) | (f2bf(c.w) << 16);
                *(uint4*)(ldsb + K_OFF + (size_t)(r0s[sI] + r) * 80 + s * 16) = w;
            }
        }
        for (int lin = tid; lin < 17 * 4; lin += 512) {
            int r = 463 + (lin >> 2), s = lin & 3;
            *(uint4*)(ldsb + K_OFF + (size_t)r * 80 + s * 16) = (uint4){0,0,0,0};
        }
    }
    // ---- stage V transposed bf16 [32][976B] + zero pad cols ----
    {
        char* vb = ldsb + V_OFF;
        const float* srcs[4] = { vg, vn, vv, vvn };
        const int rows[4] = { VN_, KNODE, KVEH, KVND };
        const int r0s[4]  = { 0, 221, 422, 443 };
        for (int sI = 0; sI < 4; ++sI) {
            const float* sp = srcs[sI] + (size_t)bh * rows[sI] * 32;
            const int n = rows[sI] * 32;
            for (int lin = tid; lin < n; lin += 512) {
                int k = lin >> 5, d = lin & 31;
                *(unsigned short*)(vb + (size_t)d * 976 + (size_t)(r0s[sI] + k) * 2) =
                    (unsigned short)f2bf(sp[lin]);
            }
        }
        for (int lin = tid; lin < 32 * 17; lin += 512) {
            int d = lin / 17, k = 463 + (lin - d * 17);
            *(unsigned short*)(vb + (size_t)d * 976 + (size_t)k * 2) = 0;
        }
    }
    __syncthreads();

    const int wave = tid >> 6, lane = tid & 63;
    if (wave >= 7) return;                 // 7 q-tiles of 16 cover P=100
    const int g = lane >> 4, qr = lane & 15;
    const int q0 = wave * 16;
    const int qe = (q0 + qr < 100) ? (q0 + qr) : 99;

    // Q fragment: B-side, col q = lane&15, dims 8g..8g+7, SCALE folded in
    short8 qf;
    {
        const float* qp = q4 + ((size_t)bh * 100 + qe) * 32 + g * 8;
        float4 a = *(const float4*)qp;
        float4 c = *(const float4*)(qp + 4);
        const float SC = 0.17677669529663687f;
        qf = (short8){ (short)f2bf(a.x*SC), (short)f2bf(a.y*SC),
                       (short)f2bf(a.z*SC), (short)f2bf(a.w*SC),
                       (short)f2bf(c.x*SC), (short)f2bf(c.y*SC),
                       (short)f2bf(c.z*SC), (short)f2bf(c.w*SC) };
    }
    char* Pw = ldsb + P_OFF + wave * 1280;
    const unsigned char* mrow = maskp + ((size_t)b * 100 + qe) * MASKP;

    f32x4 O0 = {0.f,0.f,0.f,0.f}, O1 = {0.f,0.f,0.f,0.f};
    // sources: global [0,221) masked | node [221,422) | veh [422,443) | vnd [443,463)
    attend_rng<true >(ldsb, Pw, mrow, qf, g, qr, 0,  6,  0,   224, O0, O1);
    attend_rng<false>(ldsb, Pw, mrow, qf, g, qr, 6,  13, 221, 422, O0, O1);
    attend_rng<false>(ldsb, Pw, mrow, qf, g, qr, 13, 13, 422, 443, O0, O1);
    attend_rng<false>(ldsb, Pw, mrow, qf, g, qr, 13, 14, 443, 463, O0, O1);

    if (q0 + qr < 100) {
        float* op = ctx_out + ((size_t)b * 100 + q0 + qr) * 512 + nh * 32 + 4 * g;
        *(f32x4*)op        = O0;    // dims 4g..4g+3
        *(f32x4*)(op + 16) = O1;    // dims 16+4g..16+4g+3
    }
}

// ------------------------------------------------------------------
// q-projection GEMM: [25600,528] x Wq^T -> q4 [B,NH,P,HD]
// ------------------------------------------------------------------
__global__ __launch_bounds__(256) void qproj_kernel(
    const float* __restrict__ qg, const float* __restrict__ cf,
    const float* __restrict__ Wq, float* __restrict__ q4)
{
    __shared__ float As[16][65];
    __shared__ float Bs[16][68];
    const int tid = threadIdx.x;
    const int tx = tid & 15, ty = tid >> 4;
    const int n0 = blockIdx.x * 64;
    const int m0 = blockIdx.y * 64;
    float acc[4][4] = {};
    for (int kc = 0; kc < 528; kc += 16) {
        #pragma unroll
        for (int i = 0; i < 4; i++) {
            int lin = tid + i * 256;
            int k = lin & 15, m = lin >> 4;
            int gk = kc + k;
            int row = m0 + m;
            As[k][m] = (gk < 512) ? qg[(size_t)row * 512 + gk]
                                  : cf[(size_t)row * 16 + (gk - 512)];
            Bs[k][m] = Wq[(size_t)(n0 + m) * 528 + gk];
        }
        __syncthreads();
        #pragma unroll
        for (int kk = 0; kk < 16; kk++) {
            float a[4];
            #pragma unroll
            for (int i = 0; i < 4; i++) a[i] = As[kk][ty * 4 + i];
            float4 b4 = *(const float4*)(&Bs[kk][tx * 4]);
            float bv[4] = { b4.x, b4.y, b4.z, b4.w };
            #pragma unroll
            for (int i = 0; i < 4; i++)
                #pragma unroll
                for (int j = 0; j < 4; j++)
                    acc[i][j] += a[i] * bv[j];
        }
        __syncthreads();
    }
    #pragma unroll
    for (int i = 0; i < 4; i++) {
        int row = m0 + ty * 4 + i;
        int bb = row / 100, p = row % 100;
        #pragma unroll
        for (int j = 0; j < 4; j++) {
            int col = n0 + tx * 4 + j;
            int nh = col >> 5, d = col & 31;
            q4[(((size_t)bb * NH_ + nh) * P_ + p) * HD_ + d] = acc[i][j];
        }
    }
}

// ------------------------------------------------------------------
// combine GEMM: [25600,512] x Wc^T + bias -> mha [25600,512]
// ------------------------------------------------------------------
__global__ __launch_bounds__(256) void combine_kernel(
    const float* __restrict__ ctx, const float* __restrict__ Wc,
    const float* __restrict__ bias, float* __restrict__ mha)
{
    __shared__ float As[16][65];
    __shared__ float Bs[16][68];
    const int tid = threadIdx.x;
    const int tx = tid & 15, ty = tid >> 4;
    const int n0 = blockIdx.x * 64;
    const int m0 = blockIdx.y * 64;
    float acc[4][4] = {};
    for (int kc = 0; kc < 512; kc += 16) {
        #pragma unroll
        for (int i = 0; i < 4; i++) {
            int lin = tid + i * 256;
            int k = lin & 15, m = lin >> 4;
            int gk = kc + k;
            As[k][m] = ctx[(size_t)(m0 + m) * 512 + gk];
            Bs[k][m] = Wc[(size_t)(n0 + m) * 512 + gk];
        }
        __syncthreads();
        #pragma unroll
        for (int kk = 0; kk < 16; kk++) {
            float a[4];
            #pragma unroll
            for (int i = 0; i < 4; i++) a[i] = As[kk][ty * 4 + i];
            float4 b4 = *(const float4*)(&Bs[kk][tx * 4]);
            float bv[4] = { b4.x, b4.y, b4.z, b4.w };
            #pragma unroll
            for (int i = 0; i < 4; i++)
                #pragma unroll
                for (int j = 0; j < 4; j++)
                    acc[i][j] += a[i] * bv[j];
        }
        __syncthreads();
    }
    #pragma unroll
    for (int i = 0; i < 4; i++) {
        int row = m0 + ty * 4 + i;
        #pragma unroll
        for (int j = 0; j < 4; j++) {
            int col = n0 + tx * 4 + j;
            mha[(size_t)row * 512 + col] = acc[i][j] + bias[col];
        }
    }
}

// ------------------------------------------------------------------
// logits: out[b,p,k] = sum_h mha[b,p,h] * cp[b,h,k]
// ------------------------------------------------------------------
__global__ __launch_bounds__(256) void logits_kernel(
    const float* __restrict__ mha,   // [B*P, 512]
    const float* __restrict__ cp,    // [B, 512, VN]
    float* __restrict__ out)         // [B*P, VN]
{
    __shared__ float sm[25 * 512];
    const int tid = threadIdx.x;
    const int b  = blockIdx.x >> 2;
    const int p0 = (blockIdx.x & 3) * 25;

    const float4* msrc = (const float4*)(mha + ((size_t)b * P_ + p0) * 512);
    for (int i = tid; i < 25 * 128; i += 256) ((float4*)sm)[i] = msrc[i];
    __syncthreads();

    const int k = tid;
    if (k < VN_) {
        const float* cpb = cp + (size_t)b * 512 * VN_;
        float acc[25] = {};
        for (int h = 0; h < 512; h += 4) {
            float c0 = cpb[(size_t)(h + 0) * VN_ + k];
            float c1 = cpb[(size_t)(h + 1) * VN_ + k];
            float c2 = cpb[(size_t)(h + 2) * VN_ + k];
            float c3 = cpb[(size_t)(h + 3) * VN_ + k];
            #pragma unroll
            for (int p = 0; p < 25; p++) {
                float4 m4 = *(const float4*)(sm + p * 512 + h);
                acc[p] += m4.x * c0 + m4.y * c1 + m4.z * c2 + m4.w * c3;
            }
        }
        #pragma unroll
        for (int p = 0; p < 25; p++)
            out[((size_t)b * P_ + p0 + p) * VN_ + k] = acc[p];
    }
}

// ------------------------------------------------------------------
extern "C" void kernel_launch(void* const* d_in, const int* in_sizes, int n_in,
                              void* d_out, int out_size, void* d_ws, size_t ws_size,
                              hipStream_t stream) {
    const float* qg   = (const float*)d_in[0];
    const float* kgl  = (const float*)d_in[1];
    const float* vgl  = (const float*)d_in[2];
    const float* knd  = (const float*)d_in[3];
    const float* vnd  = (const float*)d_in[4];
    const float* kvh  = (const float*)d_in[5];
    const float* vvh  = (const float*)d_in[6];
    const float* kvnd = (const float*)d_in[7];
    const float* vvnd = (const float*)d_in[8];
    const float* cf   = (const float*)d_in[9];
    const float* cp   = (const float*)d_in[10];
    const void*  mask_raw = d_in[11];
    const float* Wq   = (const float*)d_in[12];
    const float* Wc   = (const float*)d_in[13];
    const float* bias = (const float*)d_in[14];
    float* out = (float*)d_out;

    const size_t NQ = (size_t)B_ * NH_ * P_ * HD_;   // 13,107,200 f32
    float* q4buf  = (float*)d_ws;
    float* ctxbuf = q4buf + NQ;
    float* mhabuf = q4buf;                            // reuse: q dead after attn
    unsigned char* mask8 = (unsigned char*)(ctxbuf + NQ);
    const int MASKN_P = B_ * P_ * MASKP;
    int* flag = (int*)(mask8 + ((MASKN_P + 15) & ~15));

    hipFuncSetAttribute(reinterpret_cast<const void*>(attn_mfma_kernel),
                        hipFuncAttributeMaxDynamicSharedMemorySize,
                        ATTN_LDS_B);

    // ---- canonicalize mask (int32 or uint8) into padded [B*P][224] ----
    hipMemsetAsync(flag, 0, sizeof(int), stream);
    mask_detect_kernel<<<16, 256, 0, stream>>>(
        (const unsigned int*)mask_raw, 4096, flag);
    mask_repack_kernel<<<(MASKN_P + 255) / 256, 256, 0, stream>>>(
        (const unsigned char*)mask_raw, (const int*)mask_raw, flag, mask8);

    qproj_kernel<<<dim3(8, 400), 256, 0, stream>>>(qg, cf, Wq, q4buf);
    attn_mfma_kernel<<<B_ * NH_, 512, ATTN_LDS_B, stream>>>(
        q4buf, kgl, vgl, knd, vnd, kvh, vvh, kvnd, vvnd, mask8, ctxbuf);
    combine_kernel<<<dim3(8, 400), 256, 0, stream>>>(ctxbuf, Wc, bias, mhabuf);
    logits_kernel<<<B_ * 4, 256, 0, stream>>>(mhabuf, cp, out);
}

// Round 4
// 485.250 us; speedup vs baseline: 7.7033x; 2.0057x over previous
//
#include <hip/hip_runtime.h>
#include <hip/hip_bf16.h>

#define B_   256
#define P_   100
#define H_   512
#define NH_  16
#define HD_  32
#define VN_  221
#define KNODE 201
#define KVEH  21
#define KVND  20
#define CSD_ 16
#define MASKP 224                       // padded mask row stride (aligned dwords)

typedef __attribute__((ext_vector_type(8))) short short8;
typedef __attribute__((ext_vector_type(4))) float f32x4;

// ---- attention LDS layout (bytes) ----
#define K_OFF   0
#define V_OFF   38400
#define P_OFF   69632
#define ATTN_LDS_B 79872

__device__ __forceinline__ unsigned f2bf(float f) {
    union { float f; unsigned u; } x; x.f = f;
    return (x.u + 0x7FFFu + ((x.u >> 16) & 1u)) >> 16;   // RNE bf16 bits
}

// ------------------------------------------------------------------
// mask dtype probe + repack to padded [B*P][224] u8 (pad = 1 = illegal)
// ------------------------------------------------------------------
__global__ void mask_detect_kernel(const unsigned int* __restrict__ w,
                                   int nwords, int* __restrict__ flag) {
    int i = blockIdx.x * 256 + threadIdx.x;
    if (i < nwords && (w[i] & ~1u)) atomicOr(flag, 1);
}

__global__ void mask_repack_kernel(const unsigned char* __restrict__ mb,
                                   const int* __restrict__ mw,
                                   const int* __restrict__ flag,
                                   unsigned char* __restrict__ out) {
    int i = blockIdx.x * blockDim.x + threadIdx.x;
    if (i >= B_ * P_ * MASKP) return;
    int row = i / MASKP, k = i - row * MASKP;
    unsigned char v = 1;
    if (k < VN_) {
        int src = row * VN_ + k;
        v = (*flag) ? (unsigned char)(mb[src] != 0) : (unsigned char)(mw[src] != 0);
    }
    out[i] = v;
}

// ------------------------------------------------------------------
// attention (unchanged from round 3)
// ------------------------------------------------------------------
template<bool MASKED>
__device__ __forceinline__ void attend_rng(
    const char* __restrict__ ldsb, char* __restrict__ Pw,
    const unsigned char* __restrict__ mrow,
    short8 qf, int g, int qr, int c0, int c1, int lo, int hi,
    f32x4& O0, f32x4& O1)
{
    f32x4 A0 = {0.f,0.f,0.f,0.f}, A1 = {0.f,0.f,0.f,0.f};
    float ssum = 0.f;
    for (int c = c0; c <= c1; ++c) {
        #pragma unroll
        for (int t = 0; t < 2; ++t) {
            const int kb = c * 32 + t * 16;
            short8 kf = *(const short8*)(ldsb + K_OFF + (size_t)(kb + qr) * 80 + g * 16);
            f32x4 s = __builtin_amdgcn_mfma_f32_16x16x32_bf16(
                          kf, qf, (f32x4){0.f,0.f,0.f,0.f}, 0, 0, 0);
            unsigned mdw = 0;
            if (MASKED) mdw = *(const unsigned*)(mrow + kb + g * 4);
            float pv[4];
            #pragma unroll
            for (int r = 0; r < 4; ++r) {
                int key = kb + g * 4 + r;
                float sv = fminf(fmaxf(s[r], -30.f), 30.f);
                float e = __expf(sv);
                bool ok = MASKED ? (((mdw >> (8 * r)) & 255u) == 0u)
                                 : (key >= lo && key < hi);
                e = ok ? e : 0.f;
                pv[r] = e;
                ssum += e;
            }
            uint2 w;
            w.x = f2bf(pv[0]) | (f2bf(pv[1]) << 16);
            w.y = f2bf(pv[2]) | (f2bf(pv[3]) << 16);
            *(uint2*)(Pw + qr * 80 + t * 32 + g * 8) = w;
        }
        asm volatile("s_waitcnt lgkmcnt(0)" ::: "memory");
        short8 pf = *(const short8*)(Pw + qr * 80 + g * 16);
        short8 v0 = *(const short8*)(ldsb + V_OFF + (size_t)qr        * 976 + c * 64 + g * 16);
        short8 v1 = *(const short8*)(ldsb + V_OFF + (size_t)(qr + 16) * 976 + c * 64 + g * 16);
        A0 = __builtin_amdgcn_mfma_f32_16x16x32_bf16(v0, pf, A0, 0, 0, 0);
        A1 = __builtin_amdgcn_mfma_f32_16x16x32_bf16(v1, pf, A1, 0, 0, 0);
    }
    ssum += __shfl_xor(ssum, 16);
    ssum += __shfl_xor(ssum, 32);
    const float inv = 1.f / ssum;
    O0 += A0 * inv;
    O1 += A1 * inv;
}

__global__ __launch_bounds__(512, 4) void attn_mfma_kernel(
    const float* __restrict__ q4,
    const float* __restrict__ kg,  const float* __restrict__ vg,
    const float* __restrict__ kn,  const float* __restrict__ vn,
    const float* __restrict__ kv,  const float* __restrict__ vv,
    const float* __restrict__ kvn, const float* __restrict__ vvn,
    const unsigned char* __restrict__ maskp,
    float* __restrict__ ctx_out)
{
    extern __shared__ char ldsb[];
    const int tid = threadIdx.x;
    const int bh = blockIdx.x, b = bh >> 4, nh = bh & 15;

    {
        const float* srcs[4] = { kg, kn, kv, kvn };
        const int rows[4] = { VN_, KNODE, KVEH, KVND };
        const int r0s[4]  = { 0, 221, 422, 443 };
        for (int sI = 0; sI < 4; ++sI) {
            const float* sp = srcs[sI] + (size_t)bh * rows[sI] * 32;
            const int nslot = rows[sI] * 4;
            for (int lin = tid; lin < nslot; lin += 512) {
                int r = lin >> 2, s = lin & 3;
                float4 a = *(const float4*)(sp + r * 32 + s * 8);
                float4 c = *(const float4*)(sp + r * 32 + s * 8 + 4);
                uint4 w;
                w.x = f2bf(a.x) | (f2bf(a.y) << 16);
                w.y = f2bf(a.z) | (f2bf(a.w) << 16);
                w.z = f2bf(c.x) | (f2bf(c.y) << 16);
                w.w = f2bf(c.z) | (f2bf(c.w) << 16);
                *(uint4*)(ldsb + K_OFF + (size_t)(r0s[sI] + r) * 80 + s * 16) = w;
            }
        }
        for (int lin = tid; lin < 17 * 4; lin += 512) {
            int r = 463 + (lin >> 2), s = lin & 3;
            *(uint4*)(ldsb + K_OFF + (size_t)r * 80 + s * 16) = (uint4){0,0,0,0};
        }
    }
    {
        char* vb = ldsb + V_OFF;
        const float* srcs[4] = { vg, vn, vv, vvn };
        const int rows[4] = { VN_, KNODE, KVEH, KVND };
        const int r0s[4]  = { 0, 221, 422, 443 };
        for (int sI = 0; sI < 4; ++sI) {
            const float* sp = srcs[sI] + (size_t)bh * rows[sI] * 32;
            const int n = rows[sI] * 32;
            for (int lin = tid; lin < n; lin += 512) {
                int k = lin >> 5, d = lin & 31;
                *(unsigned short*)(vb + (size_t)d * 976 + (size_t)(r0s[sI] + k) * 2) =
                    (unsigned short)f2bf(sp[lin]);
            }
        }
        for (int lin = tid; lin < 32 * 17; lin += 512) {
            int d = lin / 17, k = 463 + (lin - d * 17);
            *(unsigned short*)(vb + (size_t)d * 976 + (size_t)k * 2) = 0;
        }
    }
    __syncthreads();

    const int wave = tid >> 6, lane = tid & 63;
    if (wave >= 7) return;
    const int g = lane >> 4, qr = lane & 15;
    const int q0 = wave * 16;
    const int qe = (q0 + qr < 100) ? (q0 + qr) : 99;

    short8 qf;
    {
        const float* qp = q4 + ((size_t)bh * 100 + qe) * 32 + g * 8;
        float4 a = *(const float4*)qp;
        float4 c = *(const float4*)(qp + 4);
        const float SC = 0.17677669529663687f;
        qf = (short8){ (short)f2bf(a.x*SC), (short)f2bf(a.y*SC),
                       (short)f2bf(a.z*SC), (short)f2bf(a.w*SC),
                       (short)f2bf(c.x*SC), (short)f2bf(c.y*SC),
                       (short)f2bf(c.z*SC), (short)f2bf(c.w*SC) };
    }
    char* Pw = ldsb + P_OFF + wave * 1280;
    const unsigned char* mrow = maskp + ((size_t)b * 100 + qe) * MASKP;

    f32x4 O0 = {0.f,0.f,0.f,0.f}, O1 = {0.f,0.f,0.f,0.f};
    attend_rng<true >(ldsb, Pw, mrow, qf, g, qr, 0,  6,  0,   224, O0, O1);
    attend_rng<false>(ldsb, Pw, mrow, qf, g, qr, 6,  13, 221, 422, O0, O1);
    attend_rng<false>(ldsb, Pw, mrow, qf, g, qr, 13, 13, 422, 443, O0, O1);
    attend_rng<false>(ldsb, Pw, mrow, qf, g, qr, 13, 14, 443, 463, O0, O1);

    if (q0 + qr < 100) {
        float* op = ctx_out + ((size_t)b * 100 + q0 + qr) * 512 + nh * 32 + 4 * g;
        *(f32x4*)op        = O0;
        *(f32x4*)(op + 16) = O1;
    }
}

// ------------------------------------------------------------------
// qproj MFMA: [25600,544pad] x Wq^T -> q4 [B,NH,P,HD]
// 64x64 tile, BK=32, 4 waves (2x2), each 32x32 via 2x2 16x16x32 frags
// ------------------------------------------------------------------
__global__ __launch_bounds__(256) void qproj_mfma(
    const float* __restrict__ qg, const float* __restrict__ cf,
    const float* __restrict__ Wq, float* __restrict__ q4)
{
    __shared__ char As[64 * 80];
    __shared__ char Bs[64 * 80];
    const int tid = threadIdx.x;
    const int m0 = blockIdx.y * 64, n0 = blockIdx.x * 64;
    const int r = tid >> 2, s = tid & 3;
    const int wave = tid >> 6, lane = tid & 63;
    const int wm = wave >> 1, wn = wave & 1;
    const int g = lane >> 4, qr = lane & 15;

    f32x4 acc[2][2] = {};
    for (int k0 = 0; k0 < 544; k0 += 32) {
        const int k = k0 + 8 * s;
        uint4 wa = {0,0,0,0}, wb = {0,0,0,0};
        {
            float4 a = {0,0,0,0}, c = {0,0,0,0};
            const int row = m0 + r;
            if (k < 512) {
                a = *(const float4*)(qg + (size_t)row * 512 + k);
                c = *(const float4*)(qg + (size_t)row * 512 + k + 4);
            } else if (k < 528) {
                a = *(const float4*)(cf + (size_t)row * 16 + (k - 512));
                c = *(const float4*)(cf + (size_t)row * 16 + (k - 512) + 4);
            }
            wa.x = f2bf(a.x) | (f2bf(a.y) << 16);
            wa.y = f2bf(a.z) | (f2bf(a.w) << 16);
            wa.z = f2bf(c.x) | (f2bf(c.y) << 16);
            wa.w = f2bf(c.z) | (f2bf(c.w) << 16);
        }
        {
            float4 a = {0,0,0,0}, c = {0,0,0,0};
            const int row = n0 + r;
            if (k < 528) {
                a = *(const float4*)(Wq + (size_t)row * 528 + k);
                c = *(const float4*)(Wq + (size_t)row * 528 + k + 4);
            }
            wb.x = f2bf(a.x) | (f2bf(a.y) << 16);
            wb.y = f2bf(a.z) | (f2bf(a.w) << 16);
            wb.z = f2bf(c.x) | (f2bf(c.y) << 16);
            wb.w = f2bf(c.z) | (f2bf(c.w) << 16);
        }
        __syncthreads();
        *(uint4*)(As + r * 80 + s * 16) = wa;
        *(uint4*)(Bs + r * 80 + s * 16) = wb;
        __syncthreads();
        short8 a0 = *(const short8*)(As + (wm * 32 + qr) * 80 + g * 16);
        short8 a1 = *(const short8*)(As + (wm * 32 + 16 + qr) * 80 + g * 16);
        short8 b0 = *(const short8*)(Bs + (wn * 32 + qr) * 80 + g * 16);
        short8 b1 = *(const short8*)(Bs + (wn * 32 + 16 + qr) * 80 + g * 16);
        acc[0][0] = __builtin_amdgcn_mfma_f32_16x16x32_bf16(a0, b0, acc[0][0], 0, 0, 0);
        acc[0][1] = __builtin_amdgcn_mfma_f32_16x16x32_bf16(a0, b1, acc[0][1], 0, 0, 0);
        acc[1][0] = __builtin_amdgcn_mfma_f32_16x16x32_bf16(a1, b0, acc[1][0], 0, 0, 0);
        acc[1][1] = __builtin_amdgcn_mfma_f32_16x16x32_bf16(a1, b1, acc[1][1], 0, 0, 0);
    }
    #pragma unroll
    for (int mi = 0; mi < 2; ++mi)
        #pragma unroll
        for (int ni = 0; ni < 2; ++ni)
            #pragma unroll
            for (int reg = 0; reg < 4; ++reg) {
                int m = m0 + wm * 32 + 16 * mi + 4 * g + reg;
                int n = n0 + wn * 32 + 16 * ni + qr;
                int bb = m / 100, p = m - bb * 100;
                int nh = n >> 5, d = n & 31;
                q4[(((size_t)bb * NH_ + nh) * P_ + p) * HD_ + d] = acc[mi][ni][reg];
            }
}

// ------------------------------------------------------------------
// combine MFMA: [25600,512] x Wc^T + bias -> mha [25600,512]
// ------------------------------------------------------------------
__global__ __launch_bounds__(256) void combine_mfma(
    const float* __restrict__ ctx, const float* __restrict__ Wc,
    const float* __restrict__ bias, float* __restrict__ mha)
{
    __shared__ char As[64 * 80];
    __shared__ char Bs[64 * 80];
    const int tid = threadIdx.x;
    const int m0 = blockIdx.y * 64, n0 = blockIdx.x * 64;
    const int r = tid >> 2, s = tid & 3;
    const int wave = tid >> 6, lane = tid & 63;
    const int wm = wave >> 1, wn = wave & 1;
    const int g = lane >> 4, qr = lane & 15;

    f32x4 acc[2][2] = {};
    for (int k0 = 0; k0 < 512; k0 += 32) {
        const int k = k0 + 8 * s;
        float4 a = *(const float4*)(ctx + (size_t)(m0 + r) * 512 + k);
        float4 c = *(const float4*)(ctx + (size_t)(m0 + r) * 512 + k + 4);
        uint4 wa, wb;
        wa.x = f2bf(a.x) | (f2bf(a.y) << 16);
        wa.y = f2bf(a.z) | (f2bf(a.w) << 16);
        wa.z = f2bf(c.x) | (f2bf(c.y) << 16);
        wa.w = f2bf(c.z) | (f2bf(c.w) << 16);
        a = *(const float4*)(Wc + (size_t)(n0 + r) * 512 + k);
        c = *(const float4*)(Wc + (size_t)(n0 + r) * 512 + k + 4);
        wb.x = f2bf(a.x) | (f2bf(a.y) << 16);
        wb.y = f2bf(a.z) | (f2bf(a.w) << 16);
        wb.z = f2bf(c.x) | (f2bf(c.y) << 16);
        wb.w = f2bf(c.z) | (f2bf(c.w) << 16);
        __syncthreads();
        *(uint4*)(As + r * 80 + s * 16) = wa;
        *(uint4*)(Bs + r * 80 + s * 16) = wb;
        __syncthreads();
        short8 a0 = *(const short8*)(As + (wm * 32 + qr) * 80 + g * 16);
        short8 a1 = *(const short8*)(As + (wm * 32 + 16 + qr) * 80 + g * 16);
        short8 b0 = *(const short8*)(Bs + (wn * 32 + qr) * 80 + g * 16);
        short8 b1 = *(const short8*)(Bs + (wn * 32 + 16 + qr) * 80 + g * 16);
        acc[0][0] = __builtin_amdgcn_mfma_f32_16x16x32_bf16(a0, b0, acc[0][0], 0, 0, 0);
        acc[0][1] = __builtin_amdgcn_mfma_f32_16x16x32_bf16(a0, b1, acc[0][1], 0, 0, 0);
        acc[1][0] = __builtin_amdgcn_mfma_f32_16x16x32_bf16(a1, b0, acc[1][0], 0, 0, 0);
        acc[1][1] = __builtin_amdgcn_mfma_f32_16x16x32_bf16(a1, b1, acc[1][1], 0, 0, 0);
    }
    const float bia0 = bias[n0 + wn * 32 + qr];
    const float bia1 = bias[n0 + wn * 32 + 16 + qr];
    #pragma unroll
    for (int mi = 0; mi < 2; ++mi)
        #pragma unroll
        for (int ni = 0; ni < 2; ++ni)
            #pragma unroll
            for (int reg = 0; reg < 4; ++reg) {
                int m = m0 + wm * 32 + 16 * mi + 4 * g + reg;
                int n = n0 + wn * 32 + 16 * ni + qr;
                mha[(size_t)m * 512 + n] = acc[mi][ni][reg] + (ni ? bia1 : bia0);
            }
}

// ------------------------------------------------------------------
// logits MFMA: per b, out[p,key] = sum_h mha[b,p,h]*cp[b,h,key]
// 8 waves x 16 p-rows (pad 128), N pad 224 -> 14 frags/wave, K=512
// ------------------------------------------------------------------
__global__ __launch_bounds__(512) void logits_mfma(
    const float* __restrict__ mha,   // [B*P, 512]
    const float* __restrict__ cp,    // [B, 512, VN]
    float* __restrict__ out)         // [B*P, VN]
{
    __shared__ char As[128 * 80];    // 10240
    __shared__ char Bs[224 * 80];    // 17920
    const int b = blockIdx.x;
    const int tid = threadIdx.x;
    const int wave = tid >> 6, lane = tid & 63;
    const int g = lane >> 4, qr = lane & 15;
    const int row = tid >> 2, s = tid & 3;

    f32x4 acc[14] = {};
    for (int h0 = 0; h0 < 512; h0 += 32) {
        uint4 wa = {0,0,0,0};
        if (row < 100) {
            const float* mp = mha + ((size_t)b * P_ + row) * 512 + h0 + 8 * s;
            float4 a = *(const float4*)mp;
            float4 c = *(const float4*)(mp + 4);
            wa.x = f2bf(a.x) | (f2bf(a.y) << 16);
            wa.y = f2bf(a.z) | (f2bf(a.w) << 16);
            wa.z = f2bf(c.x) | (f2bf(c.y) << 16);
            wa.w = f2bf(c.z) | (f2bf(c.w) << 16);
        }
        __syncthreads();
        *(uint4*)(As + row * 80 + s * 16) = wa;
        for (int lin = tid; lin < 224 * 8; lin += 512) {
            int kk = lin % 224, hq = lin / 224;
            int h = hq * 4;
            float v0 = 0.f, v1 = 0.f, v2 = 0.f, v3 = 0.f;
            if (kk < VN_) {
                const float* cpp = cp + ((size_t)b * 512 + h0 + h) * VN_ + kk;
                v0 = cpp[0]; v1 = cpp[VN_]; v2 = cpp[2 * VN_]; v3 = cpp[3 * VN_];
            }
            uint2 w;
            w.x = f2bf(v0) | (f2bf(v1) << 16);
            w.y = f2bf(v2) | (f2bf(v3) << 16);
            *(uint2*)(Bs + kk * 80 + h * 2) = w;
        }
        __syncthreads();
        short8 af = *(const short8*)(As + (wave * 16 + qr) * 80 + g * 16);
        #pragma unroll
        for (int ni = 0; ni < 14; ++ni) {
            short8 bf = *(const short8*)(Bs + (ni * 16 + qr) * 80 + g * 16);
            acc[ni] = __builtin_amdgcn_mfma_f32_16x16x32_bf16(af, bf, acc[ni], 0, 0, 0);
        }
    }
    #pragma unroll
    for (int ni = 0; ni < 14; ++ni) {
        int key = ni * 16 + qr;
        if (key >= VN_) continue;
        #pragma unroll
        for (int reg = 0; reg < 4; ++reg) {
            int p = wave * 16 + 4 * g + reg;
            if (p < P_)
                out[((size_t)b * P_ + p) * VN_ + key] = acc[ni][reg];
        }
    }
}

// ------------------------------------------------------------------
extern "C" void kernel_launch(void* const* d_in, const int* in_sizes, int n_in,
                              void* d_out, int out_size, void* d_ws, size_t ws_size,
                              hipStream_t stream) {
    const float* qg   = (const float*)d_in[0];
    const float* kgl  = (const float*)d_in[1];
    const float* vgl  = (const float*)d_in[2];
    const float* knd  = (const float*)d_in[3];
    const float* vnd  = (const float*)d_in[4];
    const float* kvh  = (const float*)d_in[5];
    const float* vvh  = (const float*)d_in[6];
    const float* kvnd = (const float*)d_in[7];
    const float* vvnd = (const float*)d_in[8];
    const float* cf   = (const float*)d_in[9];
    const float* cp   = (const float*)d_in[10];
    const void*  mask_raw = d_in[11];
    const float* Wq   = (const float*)d_in[12];
    const float* Wc   = (const float*)d_in[13];
    const float* bias = (const float*)d_in[14];
    float* out = (float*)d_out;

    const size_t NQ = (size_t)B_ * NH_ * P_ * HD_;   // 13,107,200 f32
    float* q4buf  = (float*)d_ws;
    float* ctxbuf = q4buf + NQ;
    float* mhabuf = q4buf;                            // reuse: q dead after attn
    unsigned char* mask8 = (unsigned char*)(ctxbuf + NQ);
    const int MASKN_P = B_ * P_ * MASKP;
    int* flag = (int*)(mask8 + ((MASKN_P + 15) & ~15));

    hipFuncSetAttribute(reinterpret_cast<const void*>(attn_mfma_kernel),
                        hipFuncAttributeMaxDynamicSharedMemorySize,
                        ATTN_LDS_B);

    hipMemsetAsync(flag, 0, sizeof(int), stream);
    mask_detect_kernel<<<16, 256, 0, stream>>>(
        (const unsigned int*)mask_raw, 4096, flag);
    mask_repack_kernel<<<(MASKN_P + 255) / 256, 256, 0, stream>>>(
        (const unsigned char*)mask_raw, (const int*)mask_raw, flag, mask8);

    qproj_mfma<<<dim3(8, 400), 256, 0, stream>>>(qg, cf, Wq, q4buf);
    attn_mfma_kernel<<<B_ * NH_, 512, ATTN_LDS_B, stream>>>(
        q4buf, kgl, vgl, knd, vnd, kvh, vvh, kvnd, vvnd, mask8, ctxbuf);
    combine_mfma<<<dim3(8, 400), 256, 0, stream>>>(ctxbuf, Wc, bias, mhabuf);
    logits_mfma<<<B_, 512, 0, stream>>>(mhabuf, cp, out);
}

// Round 5
// 443.837 us; speedup vs baseline: 8.4221x; 1.0933x over previous
//
#include <hip/hip_runtime.h>
#include <hip/hip_bf16.h>

#define B_   256
#define P_   100
#define H_   512
#define NH_  16
#define HD_  32
#define VN_  221
#define KNODE 201
#define KVEH  21
#define KVND  20
#define CSD_ 16
#define MASKP 224                       // padded mask row stride (aligned dwords)

typedef __attribute__((ext_vector_type(8))) short short8;
typedef __attribute__((ext_vector_type(4))) float f32x4;

// ---- attention LDS layout (bytes) ----
// K   : 480 rows x 80B  (32 bf16 + 16B pad; 16B-stride 5 odd -> benign)   [0, 38400)
// V^T : 32 rows  x 976B (480 keys bf16; 16B-stride 61 odd)                [38400, 69632)
#define K_OFF   0
#define V_OFF   38400
#define ATTN_LDS_B 69632

__device__ __forceinline__ unsigned cvtpk(float lo, float hi) {
    unsigned r;
    asm("v_cvt_pk_bf16_f32 %0, %1, %2" : "=v"(r) : "v"(lo), "v"(hi));
    return r;
}
__device__ __forceinline__ unsigned f2bf(float f) {
    union { float f; unsigned u; } x; x.f = f;
    return (x.u + 0x7FFFu + ((x.u >> 16) & 1u)) >> 16;   // RNE bf16 bits
}

// ------------------------------------------------------------------
// mask dtype probe + repack to padded [B*P][224] u8 (pad = 1 = illegal)
// ------------------------------------------------------------------
__global__ void mask_detect_kernel(const unsigned int* __restrict__ w,
                                   int nwords, int* __restrict__ flag) {
    int i = blockIdx.x * 256 + threadIdx.x;
    if (i < nwords && (w[i] & ~1u)) atomicOr(flag, 1);
}

__global__ void mask_repack_kernel(const unsigned char* __restrict__ mb,
                                   const int* __restrict__ mw,
                                   const int* __restrict__ flag,
                                   unsigned char* __restrict__ out) {
    int i = blockIdx.x * blockDim.x + threadIdx.x;
    if (i >= B_ * P_ * MASKP) return;
    int row = i / MASKP, k = i - row * MASKP;
    unsigned char v = 1;
    if (k < VN_) {
        int src = row * VN_ + k;
        v = (*flag) ? (unsigned char)(mb[src] != 0) : (unsigned char)(mw[src] != 0);
    }
    out[i] = v;
}

// ------------------------------------------------------------------
// one source: S^T=mfma(K,Q); exp2; pack; bpermute-gather P; O^T+=mfma(V^T,P)
// key layout: concat starts 0 / 224 / 432 / 456 (even, padded; pads zeroed)
// ------------------------------------------------------------------
template<bool MASKED, int C0, int C1, int LO, int HI>
__device__ __forceinline__ void attend_rng(
    const char* __restrict__ ldsb,
    const unsigned char* __restrict__ mrow,
    short8 qf, int g, int qr, int addrA, int addrB,
    f32x4& O0, f32x4& O1)
{
    f32x4 A0 = {0.f,0.f,0.f,0.f}, A1 = {0.f,0.f,0.f,0.f};
    float ssum = 0.f;
    #pragma unroll
    for (int c = C0; c <= C1; ++c) {
        const int kb = c * 32;
        short8 kf0 = *(const short8*)(ldsb + K_OFF + (size_t)(kb + qr) * 80 + g * 16);
        short8 kf1 = *(const short8*)(ldsb + K_OFF + (size_t)(kb + 16 + qr) * 80 + g * 16);
        f32x4 s0 = __builtin_amdgcn_mfma_f32_16x16x32_bf16(
                       kf0, qf, (f32x4){0.f,0.f,0.f,0.f}, 0, 0, 0);
        f32x4 s1 = __builtin_amdgcn_mfma_f32_16x16x32_bf16(
                       kf1, qf, (f32x4){0.f,0.f,0.f,0.f}, 0, 0, 0);
        unsigned mdw0 = 0, mdw1 = 0;
        if (MASKED) {
            mdw0 = *(const unsigned*)(mrow + kb + g * 4);
            mdw1 = *(const unsigned*)(mrow + kb + 16 + g * 4);
        }
        float e0[4], e1[4];
        #pragma unroll
        for (int r = 0; r < 4; ++r) {
            const int key0 = kb + 4 * g + r;     // g known in [0,3]
            const int key1 = key0 + 16;
            float x0 = exp2f(s0[r]);             // log2e folded into qf scale
            float x1 = exp2f(s1[r]);
            bool ok0, ok1;
            if (MASKED) {
                ok0 = ((mdw0 >> (8 * r)) & 255u) == 0u;
                ok1 = ((mdw1 >> (8 * r)) & 255u) == 0u;
            } else {
                ok0 = (key0 >= LO) & (key0 < HI);
                ok1 = (key1 >= LO) & (key1 < HI);
            }
            e0[r] = ok0 ? x0 : 0.f;
            e1[r] = ok1 ? x1 : 0.f;
            ssum += e0[r] + e1[r];
        }
        unsigned a0 = cvtpk(e0[0], e0[1]), a1 = cvtpk(e0[2], e0[3]);
        unsigned b0 = cvtpk(e1[0], e1[1]), b1 = cvtpk(e1[2], e1[3]);
        // gather PV B-frag: dst (qr,g) takes t-half (g<2 ? t0 : t1)
        // from src lanes qr+32*(g&1) and +16
        int pA0 = __builtin_amdgcn_ds_bpermute(addrA, (int)a0);
        int pA1 = __builtin_amdgcn_ds_bpermute(addrA, (int)a1);
        int pB0 = __builtin_amdgcn_ds_bpermute(addrB, (int)a0);
        int pB1 = __builtin_amdgcn_ds_bpermute(addrB, (int)a1);
        int qA0 = __builtin_amdgcn_ds_bpermute(addrA, (int)b0);
        int qA1 = __builtin_amdgcn_ds_bpermute(addrA, (int)b1);
        int qB0 = __builtin_amdgcn_ds_bpermute(addrB, (int)b0);
        int qB1 = __builtin_amdgcn_ds_bpermute(addrB, (int)b1);
        const bool sel = g < 2;
        union { int u[4]; short8 s8; } pf;
        pf.u[0] = sel ? pA0 : qA0;
        pf.u[1] = sel ? pA1 : qA1;
        pf.u[2] = sel ? pB0 : qB0;
        pf.u[3] = sel ? pB1 : qB1;
        short8 v0 = *(const short8*)(ldsb + V_OFF + (size_t)qr * 976 + kb * 2 + g * 16);
        short8 v1 = *(const short8*)(ldsb + V_OFF + (size_t)(qr + 16) * 976 + kb * 2 + g * 16);
        A0 = __builtin_amdgcn_mfma_f32_16x16x32_bf16(v0, pf.s8, A0, 0, 0, 0);
        A1 = __builtin_amdgcn_mfma_f32_16x16x32_bf16(v1, pf.s8, A1, 0, 0, 0);
    }
    ssum += __shfl_xor(ssum, 16);
    ssum += __shfl_xor(ssum, 32);
    const float inv = 1.f / ssum;
    O0 += A0 * inv;
    O1 += A1 * inv;
}

// ------------------------------------------------------------------
// MFMA attention: one block per (b,nh); 512 threads; K/V^T bf16 in LDS
// ------------------------------------------------------------------
__global__ __launch_bounds__(512, 4) void attn_mfma_kernel(
    const float* __restrict__ q4,
    const float* __restrict__ kg,  const float* __restrict__ vg,
    const float* __restrict__ kn,  const float* __restrict__ vn,
    const float* __restrict__ kv,  const float* __restrict__ vv,
    const float* __restrict__ kvn, const float* __restrict__ vvn,
    const unsigned char* __restrict__ maskp,
    float* __restrict__ ctx_out)
{
    extern __shared__ char ldsb[];
    const int tid = threadIdx.x;
    const int bh = blockIdx.x, b = bh >> 4, nh = bh & 15;

    const float* ksrc[4] = { kg, kn, kv, kvn };
    const float* vsrc[4] = { vg, vn, vv, vvn };
    const int rows[4] = { VN_, KNODE, KVEH, KVND };
    const int r0s[4]  = { 0, 224, 432, 456 };

    // ---- stage K as bf16 [480 rows][80B], zero pad rows ----
    for (int sI = 0; sI < 4; ++sI) {
        const float* sp = ksrc[sI] + (size_t)bh * rows[sI] * 32;
        const int nslot = rows[sI] * 4;
        for (int lin = tid; lin < nslot; lin += 512) {
            int r = lin >> 2, s = lin & 3;
            float4 a = *(const float4*)(sp + r * 32 + s * 8);
            float4 c = *(const float4*)(sp + r * 32 + s * 8 + 4);
            uint4 w;
            w.x = cvtpk(a.x, a.y); w.y = cvtpk(a.z, a.w);
            w.z = cvtpk(c.x, c.y); w.w = cvtpk(c.z, c.w);
            *(uint4*)(ldsb + K_OFF + (size_t)(r0s[sI] + r) * 80 + s * 16) = w;
        }
    }
    for (int lin = tid; lin < 17 * 4; lin += 512) {
        int zi = lin >> 2, s = lin & 3;
        int zr = (zi < 3) ? 221 + zi : (zi < 10) ? 422 + zi
               : (zi < 13) ? 443 + zi : 463 + zi;
        *(uint4*)(ldsb + K_OFF + (size_t)zr * 80 + s * 16) = (uint4){0,0,0,0};
    }
    // ---- stage V^T bf16 [32][976B] with pair-writes; zero pad pairs ----
    {
        char* vb = ldsb + V_OFF;
        for (int sI = 0; sI < 4; ++sI) {
            const float* sp = vsrc[sI] + (size_t)bh * rows[sI] * 32;
            const int PC = rows[sI] >> 1;
            for (int lin = tid; lin < PC * 32; lin += 512) {
                int p = lin >> 5, d = lin & 31;
                unsigned u = cvtpk(sp[(2 * p) * 32 + d], sp[(2 * p + 1) * 32 + d]);
                *(unsigned*)(vb + (size_t)d * 976 + (size_t)(r0s[sI] + 2 * p) * 2) = u;
            }
            if ((rows[sI] & 1) && tid < 32) {
                int d = tid;
                unsigned u = cvtpk(sp[(rows[sI] - 1) * 32 + d], 0.f);
                *(unsigned*)(vb + (size_t)d * 976 +
                             (size_t)(r0s[sI] + rows[sI] - 1) * 2) = u;
            }
        }
        for (int lin = tid; lin < 7 * 32; lin += 512) {
            int pi = lin >> 5, d = lin & 31;
            int pk = (pi == 0) ? 222 : (pi < 4) ? 424 + 2 * pi
                   : (pi == 4) ? 454 : 466 + 2 * pi;
            *(unsigned*)(vb + (size_t)d * 976 + (size_t)pk * 2) = 0;
        }
    }
    __syncthreads();

    const int wave = tid >> 6;
    if (wave >= 7) return;                 // 7 q-tiles of 16 cover P=100
    const int g = (tid >> 4) & 3, qr = tid & 15;
    const int q0 = wave * 16;
    const int qe = (q0 + qr < 100) ? (q0 + qr) : 99;

    // Q frag, scale*log2(e) folded in (exp2 downstream)
    short8 qf;
    {
        const float* qp = q4 + ((size_t)bh * 100 + qe) * 32 + g * 8;
        float4 a = *(const float4*)qp;
        float4 c = *(const float4*)(qp + 4);
        const float SC = 0.2550524218f;    // 32^-.5 * log2(e)
        union { unsigned u[4]; short8 s8; } q;
        q.u[0] = cvtpk(a.x * SC, a.y * SC);
        q.u[1] = cvtpk(a.z * SC, a.w * SC);
        q.u[2] = cvtpk(c.x * SC, c.y * SC);
        q.u[3] = cvtpk(c.z * SC, c.w * SC);
        qf = q.s8;
    }
    const unsigned char* mrow = maskp + ((size_t)b * 100 + qe) * MASKP;
    const int addrA = 4 * (qr + ((g & 1) << 5));
    const int addrB = addrA + 64;

    f32x4 O0 = {0.f,0.f,0.f,0.f}, O1 = {0.f,0.f,0.f,0.f};
    attend_rng<true,  0,  6,   0, 224>(ldsb, mrow, qf, g, qr, addrA, addrB, O0, O1);
    attend_rng<false, 7, 13, 224, 425>(ldsb, mrow, qf, g, qr, addrA, addrB, O0, O1);
    attend_rng<false,13, 14, 432, 453>(ldsb, mrow, qf, g, qr, addrA, addrB, O0, O1);
    attend_rng<false,14, 14, 456, 476>(ldsb, mrow, qf, g, qr, addrA, addrB, O0, O1);

    if (q0 + qr < 100) {
        float* op = ctx_out + ((size_t)b * 100 + q0 + qr) * 512 + nh * 32 + 4 * g;
        *(f32x4*)op        = O0;
        *(f32x4*)(op + 16) = O1;
    }
}

// ------------------------------------------------------------------
// qproj MFMA: [25600,544pad] x Wq^T -> q4 [B,NH,P,HD]
// ------------------------------------------------------------------
__global__ __launch_bounds__(256) void qproj_mfma(
    const float* __restrict__ qg, const float* __restrict__ cf,
    const float* __restrict__ Wq, float* __restrict__ q4)
{
    __shared__ char As[64 * 80];
    __shared__ char Bs[64 * 80];
    const int tid = threadIdx.x;
    const int m0 = blockIdx.y * 64, n0 = blockIdx.x * 64;
    const int r = tid >> 2, s = tid & 3;
    const int wave = tid >> 6, lane = tid & 63;
    const int wm = wave >> 1, wn = wave & 1;
    const int g = lane >> 4, qr = lane & 15;

    f32x4 acc[2][2] = {};
    for (int k0 = 0; k0 < 544; k0 += 32) {
        const int k = k0 + 8 * s;
        uint4 wa = {0,0,0,0}, wb = {0,0,0,0};
        {
            float4 a = {0,0,0,0}, c = {0,0,0,0};
            const int row = m0 + r;
            if (k < 512) {
                a = *(const float4*)(qg + (size_t)row * 512 + k);
                c = *(const float4*)(qg + (size_t)row * 512 + k + 4);
            } else if (k < 528) {
                a = *(const float4*)(cf + (size_t)row * 16 + (k - 512));
                c = *(const float4*)(cf + (size_t)row * 16 + (k - 512) + 4);
            }
            wa.x = f2bf(a.x) | (f2bf(a.y) << 16);
            wa.y = f2bf(a.z) | (f2bf(a.w) << 16);
            wa.z = f2bf(c.x) | (f2bf(c.y) << 16);
            wa.w = f2bf(c.z) | (f2bf(c.w) << 16);
        }
        {
            float4 a = {0,0,0,0}, c = {0,0,0,0};
            const int row = n0 + r;
            if (k < 528) {
                a = *(const float4*)(Wq + (size_t)row * 528 + k);
                c = *(const float4*)(Wq + (size_t)row * 528 + k + 4);
            }
            wb.x = f2bf(a.x) | (f2bf(a.y) << 16);
            wb.y = f2bf(a.z) | (f2bf(a.w) << 16);
            wb.z = f2bf(c.x) | (f2bf(c.y) << 16);
            wb.w = f2bf(c.z) | (f2bf(c.w) << 16);
        }
        __syncthreads();
        *(uint4*)(As + r * 80 + s * 16) = wa;
        *(uint4*)(Bs + r * 80 + s * 16) = wb;
        __syncthreads();
        short8 a0 = *(const short8*)(As + (wm * 32 + qr) * 80 + g * 16);
        short8 a1 = *(const short8*)(As + (wm * 32 + 16 + qr) * 80 + g * 16);
        short8 b0 = *(const short8*)(Bs + (wn * 32 + qr) * 80 + g * 16);
        short8 b1 = *(const short8*)(Bs + (wn * 32 + 16 + qr) * 80 + g * 16);
        acc[0][0] = __builtin_amdgcn_mfma_f32_16x16x32_bf16(a0, b0, acc[0][0], 0, 0, 0);
        acc[0][1] = __builtin_amdgcn_mfma_f32_16x16x32_bf16(a0, b1, acc[0][1], 0, 0, 0);
        acc[1][0] = __builtin_amdgcn_mfma_f32_16x16x32_bf16(a1, b0, acc[1][0], 0, 0, 0);
        acc[1][1] = __builtin_amdgcn_mfma_f32_16x16x32_bf16(a1, b1, acc[1][1], 0, 0, 0);
    }
    #pragma unroll
    for (int mi = 0; mi < 2; ++mi)
        #pragma unroll
        for (int ni = 0; ni < 2; ++ni)
            #pragma unroll
            for (int reg = 0; reg < 4; ++reg) {
                int m = m0 + wm * 32 + 16 * mi + 4 * g + reg;
                int n = n0 + wn * 32 + 16 * ni + qr;
                int bb = m / 100, p = m - bb * 100;
                int nh = n >> 5, d = n & 31;
                q4[(((size_t)bb * NH_ + nh) * P_ + p) * HD_ + d] = acc[mi][ni][reg];
            }
}

// ------------------------------------------------------------------
// combine MFMA: [25600,512] x Wc^T + bias -> mha [25600,512]
// ------------------------------------------------------------------
__global__ __launch_bounds__(256) void combine_mfma(
    const float* __restrict__ ctx, const float* __restrict__ Wc,
    const float* __restrict__ bias, float* __restrict__ mha)
{
    __shared__ char As[64 * 80];
    __shared__ char Bs[64 * 80];
    const int tid = threadIdx.x;
    const int m0 = blockIdx.y * 64, n0 = blockIdx.x * 64;
    const int r = tid >> 2, s = tid & 3;
    const int wave = tid >> 6, lane = tid & 63;
    const int wm = wave >> 1, wn = wave & 1;
    const int g = lane >> 4, qr = lane & 15;

    f32x4 acc[2][2] = {};
    for (int k0 = 0; k0 < 512; k0 += 32) {
        const int k = k0 + 8 * s;
        float4 a = *(const float4*)(ctx + (size_t)(m0 + r) * 512 + k);
        float4 c = *(const float4*)(ctx + (size_t)(m0 + r) * 512 + k + 4);
        uint4 wa, wb;
        wa.x = f2bf(a.x) | (f2bf(a.y) << 16);
        wa.y = f2bf(a.z) | (f2bf(a.w) << 16);
        wa.z = f2bf(c.x) | (f2bf(c.y) << 16);
        wa.w = f2bf(c.z) | (f2bf(c.w) << 16);
        a = *(const float4*)(Wc + (size_t)(n0 + r) * 512 + k);
        c = *(const float4*)(Wc + (size_t)(n0 + r) * 512 + k + 4);
        wb.x = f2bf(a.x) | (f2bf(a.y) << 16);
        wb.y = f2bf(a.z) | (f2bf(a.w) << 16);
        wb.z = f2bf(c.x) | (f2bf(c.y) << 16);
        wb.w = f2bf(c.z) | (f2bf(c.w) << 16);
        __syncthreads();
        *(uint4*)(As + r * 80 + s * 16) = wa;
        *(uint4*)(Bs + r * 80 + s * 16) = wb;
        __syncthreads();
        short8 a0 = *(const short8*)(As + (wm * 32 + qr) * 80 + g * 16);
        short8 a1 = *(const short8*)(As + (wm * 32 + 16 + qr) * 80 + g * 16);
        short8 b0 = *(const short8*)(Bs + (wn * 32 + qr) * 80 + g * 16);
        short8 b1 = *(const short8*)(Bs + (wn * 32 + 16 + qr) * 80 + g * 16);
        acc[0][0] = __builtin_amdgcn_mfma_f32_16x16x32_bf16(a0, b0, acc[0][0], 0, 0, 0);
        acc[0][1] = __builtin_amdgcn_mfma_f32_16x16x32_bf16(a0, b1, acc[0][1], 0, 0, 0);
        acc[1][0] = __builtin_amdgcn_mfma_f32_16x16x32_bf16(a1, b0, acc[1][0], 0, 0, 0);
        acc[1][1] = __builtin_amdgcn_mfma_f32_16x16x32_bf16(a1, b1, acc[1][1], 0, 0, 0);
    }
    const float bia0 = bias[n0 + wn * 32 + qr];
    const float bia1 = bias[n0 + wn * 32 + 16 + qr];
    #pragma unroll
    for (int mi = 0; mi < 2; ++mi)
        #pragma unroll
        for (int ni = 0; ni < 2; ++ni)
            #pragma unroll
            for (int reg = 0; reg < 4; ++reg) {
                int m = m0 + wm * 32 + 16 * mi + 4 * g + reg;
                int n = n0 + wn * 32 + 16 * ni + qr;
                mha[(size_t)m * 512 + n] = acc[mi][ni][reg] + (ni ? bia1 : bia0);
            }
}

// ------------------------------------------------------------------
// logits MFMA: per b, out[p,key] = sum_h mha[b,p,h]*cp[b,h,key]
// ------------------------------------------------------------------
__global__ __launch_bounds__(512) void logits_mfma(
    const float* __restrict__ mha,   // [B*P, 512]
    const float* __restrict__ cp,    // [B, 512, VN]
    float* __restrict__ out)         // [B*P, VN]
{
    __shared__ char As[128 * 80];
    __shared__ char Bs[224 * 80];
    const int b = blockIdx.x;
    const int tid = threadIdx.x;
    const int wave = tid >> 6, lane = tid & 63;
    const int g = lane >> 4, qr = lane & 15;
    const int row = tid >> 2, s = tid & 3;

    f32x4 acc[14] = {};
    for (int h0 = 0; h0 < 512; h0 += 32) {
        uint4 wa = {0,0,0,0};
        if (row < 100) {
            const float* mp = mha + ((size_t)b * P_ + row) * 512 + h0 + 8 * s;
            float4 a = *(const float4*)mp;
            float4 c = *(const float4*)(mp + 4);
            wa.x = f2bf(a.x) | (f2bf(a.y) << 16);
            wa.y = f2bf(a.z) | (f2bf(a.w) << 16);
            wa.z = f2bf(c.x) | (f2bf(c.y) << 16);
            wa.w = f2bf(c.z) | (f2bf(c.w) << 16);
        }
        __syncthreads();
        *(uint4*)(As + row * 80 + s * 16) = wa;
        for (int lin = tid; lin < 224 * 8; lin += 512) {
            int kk = lin % 224, hq = lin / 224;
            int h = hq * 4;
            float v0 = 0.f, v1 = 0.f, v2 = 0.f, v3 = 0.f;
            if (kk < VN_) {
                const float* cpp = cp + ((size_t)b * 512 + h0 + h) * VN_ + kk;
                v0 = cpp[0]; v1 = cpp[VN_]; v2 = cpp[2 * VN_]; v3 = cpp[3 * VN_];
            }
            uint2 w;
            w.x = f2bf(v0) | (f2bf(v1) << 16);
            w.y = f2bf(v2) | (f2bf(v3) << 16);
            *(uint2*)(Bs + kk * 80 + h * 2) = w;
        }
        __syncthreads();
        short8 af = *(const short8*)(As + (wave * 16 + qr) * 80 + g * 16);
        #pragma unroll
        for (int ni = 0; ni < 14; ++ni) {
            short8 bf = *(const short8*)(Bs + (ni * 16 + qr) * 80 + g * 16);
            acc[ni] = __builtin_amdgcn_mfma_f32_16x16x32_bf16(af, bf, acc[ni], 0, 0, 0);
        }
    }
    #pragma unroll
    for (int ni = 0; ni < 14; ++ni) {
        int key = ni * 16 + qr;
        if (key >= VN_) continue;
        #pragma unroll
        for (int reg = 0; reg < 4; ++reg) {
            int p = wave * 16 + 4 * g + reg;
            if (p < P_)
                out[((size_t)b * P_ + p) * VN_ + key] = acc[ni][reg];
        }
    }
}

// ------------------------------------------------------------------
extern "C" void kernel_launch(void* const* d_in, const int* in_sizes, int n_in,
                              void* d_out, int out_size, void* d_ws, size_t ws_size,
                              hipStream_t stream) {
    const float* qg   = (const float*)d_in[0];
    const float* kgl  = (const float*)d_in[1];
    const float* vgl  = (const float*)d_in[2];
    const float* knd  = (const float*)d_in[3];
    const float* vnd  = (const float*)d_in[4];
    const float* kvh  = (const float*)d_in[5];
    const float* vvh  = (const float*)d_in[6];
    const float* kvnd = (const float*)d_in[7];
    const float* vvnd = (const float*)d_in[8];
    const float* cf   = (const float*)d_in[9];
    const float* cp   = (const float*)d_in[10];
    const void*  mask_raw = d_in[11];
    const float* Wq   = (const float*)d_in[12];
    const float* Wc   = (const float*)d_in[13];
    const float* bias = (const float*)d_in[14];
    float* out = (float*)d_out;

    const size_t NQ = (size_t)B_ * NH_ * P_ * HD_;   // 13,107,200 f32
    float* q4buf  = (float*)d_ws;
    float* ctxbuf = q4buf + NQ;
    float* mhabuf = q4buf;                            // reuse: q dead after attn
    unsigned char* mask8 = (unsigned char*)(ctxbuf + NQ);
    const int MASKN_P = B_ * P_ * MASKP;
    int* flag = (int*)(mask8 + ((MASKN_P + 15) & ~15));

    hipFuncSetAttribute(reinterpret_cast<const void*>(attn_mfma_kernel),
                        hipFuncAttributeMaxDynamicSharedMemorySize,
                        ATTN_LDS_B);

    hipMemsetAsync(flag, 0, sizeof(int), stream);
    mask_detect_kernel<<<16, 256, 0, stream>>>(
        (const unsigned int*)mask_raw, 4096, flag);
    mask_repack_kernel<<<(MASKN_P + 255) / 256, 256, 0, stream>>>(
        (const unsigned char*)mask_raw, (const int*)mask_raw, flag, mask8);

    qproj_mfma<<<dim3(8, 400), 256, 0, stream>>>(qg, cf, Wq, q4buf);
    attn_mfma_kernel<<<B_ * NH_, 512, ATTN_LDS_B, stream>>>(
        q4buf, kgl, vgl, knd, vnd, kvh, vvh, kvnd, vvnd, mask8, ctxbuf);
    combine_mfma<<<dim3(8, 400), 256, 0, stream>>>(ctxbuf, Wc, bias, mhabuf);
    logits_mfma<<<B_, 512, 0, stream>>>(mhabuf, cp, out);
}